// Round 4
// baseline (199.295 us; speedup 1.0000x reference)
//
#include <hip/hip_runtime.h>

#define BATCH  32768
#define ADIM   16
#define HDIM   256
#define DDIM   128
#define KCODES 2048
#define MROWS  32    // batch rows per block
#define SA     264   // LDS row stride in u16 (256 cols + 8 pad; 528 B, 16B-aligned)

typedef unsigned short u16;
typedef short s16x8 __attribute__((ext_vector_type(8)));   // 8 x bf16 bits (MFMA frag)
typedef u16   u16x8 __attribute__((ext_vector_type(8)));
typedef float f32x4 __attribute__((ext_vector_type(4)));

__device__ __forceinline__ float b2f(u16 u) {
    return __uint_as_float(((unsigned)u) << 16);
}
__device__ __forceinline__ u16 f2b(float f) {
    unsigned u = __float_as_uint(f);
    u += 0x7fffu + ((u >> 16) & 1u);   // RNE
    return (u16)(u >> 16);
}
__device__ __forceinline__ s16x8 ldb8(const u16* p) {
    return *reinterpret_cast<const s16x8*>(p);
}

// Wave-level GEMM: C(MT*16 x NT*16) += A(MT*16 x KC*32, LDS bf16) * W^T, W (N,K) bf16 row-major.
template<int MT, int NT, int KC>
__device__ __forceinline__ void mm_tile(const u16* __restrict__ Alds, int strideA,
                                        const u16* __restrict__ W, int Kdim, int n0,
                                        int lrow, int kq, f32x4 (&acc)[MT][NT])
{
    #pragma unroll
    for (int kc = 0; kc < KC; ++kc) {
        const int k = kc * 32 + kq;
        s16x8 a[MT], b[NT];
        #pragma unroll
        for (int i = 0; i < MT; ++i) a[i] = ldb8(Alds + (i * 16 + lrow) * strideA + k);
        #pragma unroll
        for (int j = 0; j < NT; ++j) b[j] = ldb8(W + (n0 + j * 16 + lrow) * Kdim + k);
        #pragma unroll
        for (int i = 0; i < MT; ++i)
            #pragma unroll
            for (int j = 0; j < NT; ++j)
                acc[i][j] = __builtin_amdgcn_mfma_f32_16x16x32_bf16(a[i], b[j], acc[i][j], 0, 0, 0);
    }
}

// Epilogue: bias (fp32) + optional relu, store bf16 to LDS. C/D map: row=quad*4+r, col=lane&15.
template<int MT, int NT>
__device__ __forceinline__ void epilogue_st(u16* __restrict__ out, int strideO,
                                            const float* __restrict__ bias, int n0,
                                            int lrow, int quad, bool relu, f32x4 (&acc)[MT][NT])
{
    #pragma unroll
    for (int j = 0; j < NT; ++j) {
        const float bv = bias[n0 + j * 16 + lrow];
        #pragma unroll
        for (int i = 0; i < MT; ++i)
            #pragma unroll
            for (int r = 0; r < 4; ++r) {
                float v = acc[i][j][r] + bv;
                if (relu) v = fmaxf(v, 0.f);
                out[(i * 16 + quad * 4 + r) * strideO + n0 + j * 16 + lrow] = f2b(v);
            }
    }
}

// ---------------- prep: convert ALL weights + codebook fp32->bf16, E row norms, zero sums.
// Static block->segment map: [0,256)=E(+norms), then We1(4) We2(64) We3(32) Wd1(32) Wd2(64) Wh(4).
__global__ __launch_bounds__(256) void vqvae_prep(
    const float* __restrict__ Ef,   u16* __restrict__ bE,
    const float* __restrict__ We1f, u16* __restrict__ bWe1,
    const float* __restrict__ We2f, u16* __restrict__ bWe2,
    const float* __restrict__ We3f, u16* __restrict__ bWe3,
    const float* __restrict__ Wd1f, u16* __restrict__ bWd1,
    const float* __restrict__ Wd2f, u16* __restrict__ bWd2,
    const float* __restrict__ Whf,  u16* __restrict__ bWh,
    float* __restrict__ ws)
{
    const int b = blockIdx.x, t = threadIdx.x;
    if (b == 0 && t < 2) ws[t] = 0.f;
    if (b < 256) {
        // E: 1024 elems/block = 8 rows of 128; 32 consecutive threads per row.
        const int i = b * 1024 + t * 4;
        const float4 v = *reinterpret_cast<const float4*>(Ef + i);
        ushort4 o;
        o.x = f2b(v.x); o.y = f2b(v.y); o.z = f2b(v.z); o.w = f2b(v.w);
        *reinterpret_cast<ushort4*>(bE + i) = o;
        float s = b2f(o.x) * b2f(o.x) + b2f(o.y) * b2f(o.y)
                + b2f(o.z) * b2f(o.z) + b2f(o.w) * b2f(o.w);
        #pragma unroll
        for (int off = 1; off < 32; off <<= 1) s += __shfl_xor(s, off, 64);
        if ((t & 31) == 0) ws[2 + b * 8 + (t >> 5)] = s;
    } else {
        const float* src; u16* dst; int c;
        const int rb = b - 256;
        if      (rb <   4) { src = We1f; dst = bWe1; c = rb; }
        else if (rb <  68) { src = We2f; dst = bWe2; c = rb - 4; }
        else if (rb < 100) { src = We3f; dst = bWe3; c = rb - 68; }
        else if (rb < 132) { src = Wd1f; dst = bWd1; c = rb - 100; }
        else if (rb < 196) { src = Wd2f; dst = bWd2; c = rb - 132; }
        else               { src = Whf;  dst = bWh;  c = rb - 196; }
        const int i = c * 1024 + t * 4;
        const float4 v = *reinterpret_cast<const float4*>(src + i);
        ushort4 o;
        o.x = f2b(v.x); o.y = f2b(v.y); o.z = f2b(v.z); o.w = f2b(v.w);
        *reinterpret_cast<ushort4*>(dst + i) = o;
    }
}

// ---------------- main fused kernel: 32 batch rows per block, 4 waves split the N dim.
__global__ __launch_bounds__(256, 4) void ActionVQVAE_49452253446164_kernel(
    const float* __restrict__ action,
    const u16* __restrict__ We1, const float* __restrict__ be1,
    const u16* __restrict__ We2, const float* __restrict__ be2,
    const u16* __restrict__ We3, const float* __restrict__ be3,
    const u16* __restrict__ E,
    const u16* __restrict__ Wd1, const float* __restrict__ bd1,
    const u16* __restrict__ Wd2, const float* __restrict__ bd2,
    const u16* __restrict__ Wh,  const float* __restrict__ bh,
    const float* __restrict__ enorms, float* __restrict__ sums)
{
    // buf cols 0..255: h1 -> h2 -> (q | d1) -> d2 (in-place); cols 128..255 hold enc (stages 3..5).
    __shared__ u16   buf[MROWS * SA];
    __shared__ float red_val[4][MROWS];
    __shared__ int   red_idx[4][MROWS];
    __shared__ int   qidx[MROWS];
    __shared__ float wsum[8];

    const int tid  = threadIdx.x;
    const int wave = tid >> 6;
    const int lane = tid & 63;
    const int lrow = lane & 15;
    const int quad = lane >> 4;
    const int kq   = quad * 8;
    const int base = blockIdx.x * MROWS;

    float vq_acc = 0.f, rec_acc = 0.f;

    // ---------- Stage 1: h1 = relu(action @ We1^T + be1) -> buf  (K=16, zero-padded to 32)
    {
        const int n0 = wave * 64;
        f32x4 acc[2][4];
        #pragma unroll
        for (int i = 0; i < 2; ++i)
            #pragma unroll
            for (int j = 0; j < 4; ++j) { f32x4 z = {0.f, 0.f, 0.f, 0.f}; acc[i][j] = z; }
        s16x8 a[2], b[4];
        s16x8 zf = {0, 0, 0, 0, 0, 0, 0, 0};
        #pragma unroll
        for (int i = 0; i < 2; ++i) a[i] = zf;
        #pragma unroll
        for (int j = 0; j < 4; ++j) b[j] = zf;
        if (quad < 2) {
            #pragma unroll
            for (int i = 0; i < 2; ++i) {
                const float* p = action + (base + i * 16 + lrow) * ADIM + kq;
                const float4 v0 = *reinterpret_cast<const float4*>(p);
                const float4 v1 = *reinterpret_cast<const float4*>(p + 4);
                s16x8 f;
                f[0] = (short)f2b(v0.x); f[1] = (short)f2b(v0.y);
                f[2] = (short)f2b(v0.z); f[3] = (short)f2b(v0.w);
                f[4] = (short)f2b(v1.x); f[5] = (short)f2b(v1.y);
                f[6] = (short)f2b(v1.z); f[7] = (short)f2b(v1.w);
                a[i] = f;
            }
            #pragma unroll
            for (int j = 0; j < 4; ++j) b[j] = ldb8(We1 + (n0 + j * 16 + lrow) * ADIM + kq);
        }
        #pragma unroll
        for (int i = 0; i < 2; ++i)
            #pragma unroll
            for (int j = 0; j < 4; ++j)
                acc[i][j] = __builtin_amdgcn_mfma_f32_16x16x32_bf16(a[i], b[j], acc[i][j], 0, 0, 0);
        epilogue_st<2, 4>(buf, SA, be1, n0, lrow, quad, true, acc);
    }
    __syncthreads();

    // ---------- Stage 2: h2 = relu(h1 @ We2^T + be2) -> buf (in place)
    {
        const int n0 = wave * 64;
        f32x4 acc[2][4];
        #pragma unroll
        for (int i = 0; i < 2; ++i)
            #pragma unroll
            for (int j = 0; j < 4; ++j) { f32x4 z = {0.f, 0.f, 0.f, 0.f}; acc[i][j] = z; }
        mm_tile<2, 4, 8>(buf, SA, We2, HDIM, n0, lrow, kq, acc);
        __syncthreads();                       // all waves done reading h1
        epilogue_st<2, 4>(buf, SA, be2, n0, lrow, quad, true, acc);
    }
    __syncthreads();

    // ---------- Stage 3: enc = h2 @ We3^T + be3 -> buf cols 128..255
    {
        const int n0 = wave * 32;
        f32x4 acc[2][2];
        #pragma unroll
        for (int i = 0; i < 2; ++i)
            #pragma unroll
            for (int j = 0; j < 2; ++j) { f32x4 z = {0.f, 0.f, 0.f, 0.f}; acc[i][j] = z; }
        mm_tile<2, 2, 8>(buf, SA, We3, HDIM, n0, lrow, kq, acc);
        __syncthreads();                       // all waves done reading h2
        epilogue_st<2, 2>(buf + 128, SA, be3, n0, lrow, quad, false, acc);
    }
    __syncthreads();

    // ---------- Stage 4: argmin_k of d2 = |e_k|^2 - 2*enc.e_k  (|enc|^2 is row-constant)
    {
        s16x8 afr[4][2];                       // hoisted enc fragments [kc][i]
        #pragma unroll
        for (int kc = 0; kc < 4; ++kc) {
            const int k = kc * 32 + kq;
            #pragma unroll
            for (int i = 0; i < 2; ++i) afr[kc][i] = ldb8(buf + (i * 16 + lrow) * SA + 128 + k);
        }
        float minv[8]; int mini[8];
        #pragma unroll
        for (int s = 0; s < 8; ++s) { minv[s] = 3.4e38f; mini[s] = 0; }

        for (int cb = wave * 512; cb < wave * 512 + 512; cb += 64) {
            f32x4 acc[2][4];
            #pragma unroll
            for (int i = 0; i < 2; ++i)
                #pragma unroll
                for (int j = 0; j < 4; ++j) { f32x4 z = {0.f, 0.f, 0.f, 0.f}; acc[i][j] = z; }
            #pragma unroll
            for (int kc = 0; kc < 4; ++kc) {
                const int k = kc * 32 + kq;
                s16x8 b[4];
                #pragma unroll
                for (int j = 0; j < 4; ++j) b[j] = ldb8(E + (cb + j * 16 + lrow) * DDIM + k);
                #pragma unroll
                for (int i = 0; i < 2; ++i)
                    #pragma unroll
                    for (int j = 0; j < 4; ++j)
                        acc[i][j] = __builtin_amdgcn_mfma_f32_16x16x32_bf16(afr[kc][i], b[j], acc[i][j], 0, 0, 0);
            }
            float en[4];
            #pragma unroll
            for (int j = 0; j < 4; ++j) en[j] = enorms[cb + j * 16 + lrow];
            #pragma unroll
            for (int i = 0; i < 2; ++i)
                #pragma unroll
                for (int j = 0; j < 4; ++j)
                    #pragma unroll
                    for (int r = 0; r < 4; ++r) {
                        const float d2 = en[j] - 2.f * acc[i][j][r];
                        const int s = i * 4 + r;
                        if (d2 < minv[s]) { minv[s] = d2; mini[s] = cb + j * 16 + lrow; }
                    }
        }
        // reduce across the 16 lanes of each quad-group (16 candidate cols per row-slot)
        #pragma unroll
        for (int off = 1; off < 16; off <<= 1) {
            #pragma unroll
            for (int s = 0; s < 8; ++s) {
                const float ov = __shfl_xor(minv[s], off, 64);
                const int   oi = __shfl_xor(mini[s], off, 64);
                if (ov < minv[s] || (ov == minv[s] && oi < mini[s])) { minv[s] = ov; mini[s] = oi; }
            }
        }
        if (lrow == 0) {
            #pragma unroll
            for (int i = 0; i < 2; ++i)
                #pragma unroll
                for (int r = 0; r < 4; ++r) {
                    red_val[wave][i * 16 + quad * 4 + r] = minv[i * 4 + r];
                    red_idx[wave][i * 16 + quad * 4 + r] = mini[i * 4 + r];
                }
        }
    }
    __syncthreads();
    if (tid < MROWS) {
        float bv = red_val[0][tid]; int bi = red_idx[0][tid];
        #pragma unroll
        for (int w = 1; w < 4; ++w) {
            const float v = red_val[w][tid]; const int ii = red_idx[w][tid];
            if (v < bv || (v == bv && ii < bi)) { bv = v; bi = ii; }
        }
        qidx[tid] = bi;
    }
    __syncthreads();

    // ---------- Stage 5: gather q -> buf cols 0..127; accumulate vq = sum (enc - q)^2
    {
        const int row = tid >> 3;              // 32 rows, 8 threads/row
        const int c0  = (tid & 7) * 16;        // 16 cols/thread (2 x 16B vectors)
        const int code = qidx[row];
        #pragma unroll
        for (int c = 0; c < 16; c += 8) {
            const u16x8 qv = *reinterpret_cast<const u16x8*>(E + code * DDIM + c0 + c);
            const u16x8 ev = *reinterpret_cast<const u16x8*>(buf + row * SA + 128 + c0 + c);
            *reinterpret_cast<u16x8*>(buf + row * SA + c0 + c) = qv;
            #pragma unroll
            for (int t = 0; t < 8; ++t) {
                const float d = b2f(ev[t]) - b2f(qv[t]);
                vq_acc += d * d;
            }
        }
    }
    __syncthreads();

    // ---------- Stage 6: d1 = relu(q @ Wd1^T + bd1) -> buf (reads cols 0..127, writes 0..255)
    {
        const int n0 = wave * 64;
        f32x4 acc[2][4];
        #pragma unroll
        for (int i = 0; i < 2; ++i)
            #pragma unroll
            for (int j = 0; j < 4; ++j) { f32x4 z = {0.f, 0.f, 0.f, 0.f}; acc[i][j] = z; }
        mm_tile<2, 4, 4>(buf, SA, Wd1, DDIM, n0, lrow, kq, acc);
        __syncthreads();
        epilogue_st<2, 4>(buf, SA, bd1, n0, lrow, quad, true, acc);
    }
    __syncthreads();

    // ---------- Stage 7: d2 = relu(d1 @ Wd2^T + bd2) -> buf (in place)
    {
        const int n0 = wave * 64;
        f32x4 acc[2][4];
        #pragma unroll
        for (int i = 0; i < 2; ++i)
            #pragma unroll
            for (int j = 0; j < 4; ++j) { f32x4 z = {0.f, 0.f, 0.f, 0.f}; acc[i][j] = z; }
        mm_tile<2, 4, 8>(buf, SA, Wd2, HDIM, n0, lrow, kq, acc);
        __syncthreads();
        epilogue_st<2, 4>(buf, SA, bd2, n0, lrow, quad, true, acc);
    }
    __syncthreads();

    // ---------- Stage 8: recons = tanh(d2 @ Wh^T + bh); accumulate (recons - action)^2 (fp32)
    if (wave < 2) {
        const int m0 = wave * 16;
        f32x4 acc = {0.f, 0.f, 0.f, 0.f};
        #pragma unroll
        for (int kc = 0; kc < 8; ++kc) {
            const int k = kc * 32 + kq;
            s16x8 a = ldb8(buf + (m0 + lrow) * SA + k);
            s16x8 b = ldb8(Wh + lrow * HDIM + k);
            acc = __builtin_amdgcn_mfma_f32_16x16x32_bf16(a, b, acc, 0, 0, 0);
        }
        const float bias = bh[lrow];
        #pragma unroll
        for (int r = 0; r < 4; ++r) {
            const int row = m0 + quad * 4 + r;
            const float v = tanhf(acc[r] + bias);
            const float av = action[(base + row) * ADIM + lrow];
            const float d = v - av;
            rec_acc += d * d;
        }
    }

    // ---------- block reduction + atomics
    #pragma unroll
    for (int off = 1; off < 64; off <<= 1) {
        vq_acc  += __shfl_xor(vq_acc,  off, 64);
        rec_acc += __shfl_xor(rec_acc, off, 64);
    }
    if (lane == 0) { wsum[wave] = rec_acc; wsum[4 + wave] = vq_acc; }
    __syncthreads();
    if (tid == 0) {
        atomicAdd(&sums[0], wsum[0] + wsum[1] + wsum[2] + wsum[3]);
        atomicAdd(&sums[1], wsum[4] + wsum[5] + wsum[6] + wsum[7]);
    }
}

__global__ void vqvae_final(const float* __restrict__ sums, float* __restrict__ out)
{
    if (threadIdx.x == 0 && blockIdx.x == 0) {
        const float recons_loss = sums[0] / (float)(BATCH * ADIM);
        const float vq_loss     = 1.25f * (sums[1] / (float)(BATCH * DDIM));
        out[0] = recons_loss + vq_loss;
    }
}

extern "C" void kernel_launch(void* const* d_in, const int* in_sizes, int n_in,
                              void* d_out, int out_size, void* d_ws, size_t ws_size,
                              hipStream_t stream)
{
    const float* action = (const float*)d_in[0];
    const float* We1f = (const float*)d_in[1];
    const float* be1  = (const float*)d_in[2];
    const float* We2f = (const float*)d_in[3];
    const float* be2  = (const float*)d_in[4];
    const float* We3f = (const float*)d_in[5];
    const float* be3  = (const float*)d_in[6];
    const float* Ef   = (const float*)d_in[7];
    const float* Wd1f = (const float*)d_in[8];
    const float* bd1  = (const float*)d_in[9];
    const float* Wd2f = (const float*)d_in[10];
    const float* bd2  = (const float*)d_in[11];
    const float* Whf  = (const float*)d_in[12];
    const float* bh   = (const float*)d_in[13];

    float* ws = (float*)d_ws;          // [0..1] sums, [2..2049] enorms
    u16* wb = (u16*)(ws + 2052);       // bf16 area, 16B-aligned (8208 B offset)
    u16* bE   = wb;                    // 262144
    u16* bWe1 = bE   + KCODES * DDIM;  // 4096
    u16* bWe2 = bWe1 + HDIM * ADIM;    // 65536
    u16* bWe3 = bWe2 + HDIM * HDIM;    // 32768
    u16* bWd1 = bWe3 + DDIM * HDIM;    // 32768
    u16* bWd2 = bWd1 + HDIM * DDIM;    // 65536
    u16* bWh  = bWd2 + HDIM * HDIM;    // 4096

    vqvae_prep<<<456, 256, 0, stream>>>(Ef, bE, We1f, bWe1, We2f, bWe2, We3f, bWe3,
                                        Wd1f, bWd1, Wd2f, bWd2, Whf, bWh, ws);
    ActionVQVAE_49452253446164_kernel<<<BATCH / MROWS, 256, 0, stream>>>(
        action, bWe1, be1, bWe2, be2, bWe3, be3,
        bE, bWd1, bd1, bWd2, bd2, bWh, bh,
        ws + 2, ws);
    vqvae_final<<<1, 64, 0, stream>>>(ws, (float*)d_out);
}

// Round 5
// 169.191 us; speedup vs baseline: 1.1779x; 1.1779x over previous
//
#include <hip/hip_runtime.h>

#define BATCH  32768
#define ADIM   16
#define HDIM   256
#define DDIM   128
#define KCODES 2048
#define MROWS  64    // batch rows per block
#define NWAVE  8     // 512-thread blocks
#define SA     264   // LDS row stride in u16 (256 cols + 8 pad; 528 B, 16B-aligned)

typedef unsigned short u16;
typedef short s16x8 __attribute__((ext_vector_type(8)));   // 8 x bf16 bits (MFMA frag)
typedef u16   u16x8 __attribute__((ext_vector_type(8)));
typedef float f32x4 __attribute__((ext_vector_type(4)));

__device__ __forceinline__ float b2f(u16 u) {
    return __uint_as_float(((unsigned)u) << 16);
}
__device__ __forceinline__ u16 f2b(float f) {
    unsigned u = __float_as_uint(f);
    u += 0x7fffu + ((u >> 16) & 1u);   // RNE
    return (u16)(u >> 16);
}
__device__ __forceinline__ s16x8 ldb8(const u16* p) {
    return *reinterpret_cast<const s16x8*>(p);
}

// Wave-level GEMM: C(64 x NT*16) += A(64 x KC*32, LDS bf16) * W^T, W (N,K) bf16 row-major.
template<int NT, int KC>
__device__ __forceinline__ void mm_tile(const u16* __restrict__ Alds,
                                        const u16* __restrict__ W, int Kdim, int n0,
                                        int lrow, int kq, f32x4 (&acc)[4][NT])
{
    #pragma unroll
    for (int kc = 0; kc < KC; ++kc) {
        const int k = kc * 32 + kq;
        s16x8 a[4], b[NT];
        #pragma unroll
        for (int i = 0; i < 4; ++i) a[i] = ldb8(Alds + (i * 16 + lrow) * SA + k);
        #pragma unroll
        for (int j = 0; j < NT; ++j) b[j] = ldb8(W + (n0 + j * 16 + lrow) * Kdim + k);
        #pragma unroll
        for (int i = 0; i < 4; ++i)
            #pragma unroll
            for (int j = 0; j < NT; ++j)
                acc[i][j] = __builtin_amdgcn_mfma_f32_16x16x32_bf16(a[i], b[j], acc[i][j], 0, 0, 0);
    }
}

// Epilogue: bias (fp32) + optional relu, store bf16 to LDS. C/D map: row=quad*4+r, col=lane&15.
template<int NT>
__device__ __forceinline__ void epilogue_st(u16* __restrict__ out,
                                            const float* __restrict__ bias, int n0,
                                            int lrow, int quad, bool relu, f32x4 (&acc)[4][NT])
{
    #pragma unroll
    for (int j = 0; j < NT; ++j) {
        const float bv = bias[n0 + j * 16 + lrow];
        #pragma unroll
        for (int i = 0; i < 4; ++i)
            #pragma unroll
            for (int r = 0; r < 4; ++r) {
                float v = acc[i][j][r] + bv;
                if (relu) v = fmaxf(v, 0.f);
                out[(i * 16 + quad * 4 + r) * SA + n0 + j * 16 + lrow] = f2b(v);
            }
    }
}

// ---------------- prep: convert weights + codebook fp32->bf16, E row norms, zero sums+counter.
// Block map: [0,256)=E(+norms), then We1(4) We2(64) We3(32) Wd1(32) Wd2(64) Wh(4).
__global__ __launch_bounds__(256) void vqvae_prep(
    const float* __restrict__ Ef,   u16* __restrict__ bE,
    const float* __restrict__ We1f, u16* __restrict__ bWe1,
    const float* __restrict__ We2f, u16* __restrict__ bWe2,
    const float* __restrict__ We3f, u16* __restrict__ bWe3,
    const float* __restrict__ Wd1f, u16* __restrict__ bWd1,
    const float* __restrict__ Wd2f, u16* __restrict__ bWd2,
    const float* __restrict__ Whf,  u16* __restrict__ bWh,
    float* __restrict__ ws)
{
    const int b = blockIdx.x, t = threadIdx.x;
    if (b == 0 && t < 2) ws[t] = 0.f;
    if (b == 0 && t == 2) *reinterpret_cast<unsigned*>(ws + 2050) = 0u;
    if (b < 256) {
        // E: 1024 elems/block = 8 rows of 128; 32 consecutive threads per row.
        const int i = b * 1024 + t * 4;
        const float4 v = *reinterpret_cast<const float4*>(Ef + i);
        ushort4 o;
        o.x = f2b(v.x); o.y = f2b(v.y); o.z = f2b(v.z); o.w = f2b(v.w);
        *reinterpret_cast<ushort4*>(bE + i) = o;
        float s = b2f(o.x) * b2f(o.x) + b2f(o.y) * b2f(o.y)
                + b2f(o.z) * b2f(o.z) + b2f(o.w) * b2f(o.w);
        #pragma unroll
        for (int off = 1; off < 32; off <<= 1) s += __shfl_xor(s, off, 64);
        if ((t & 31) == 0) ws[2 + b * 8 + (t >> 5)] = s;
    } else {
        const float* src; u16* dst; int c;
        const int rb = b - 256;
        if      (rb <   4) { src = We1f; dst = bWe1; c = rb; }
        else if (rb <  68) { src = We2f; dst = bWe2; c = rb - 4; }
        else if (rb < 100) { src = We3f; dst = bWe3; c = rb - 68; }
        else if (rb < 132) { src = Wd1f; dst = bWd1; c = rb - 100; }
        else if (rb < 196) { src = Wd2f; dst = bWd2; c = rb - 132; }
        else               { src = Whf;  dst = bWh;  c = rb - 196; }
        const int i = c * 1024 + t * 4;
        const float4 v = *reinterpret_cast<const float4*>(src + i);
        ushort4 o;
        o.x = f2b(v.x); o.y = f2b(v.y); o.z = f2b(v.z); o.w = f2b(v.w);
        *reinterpret_cast<ushort4*>(dst + i) = o;
    }
}

// ---------------- main fused kernel: 64 rows/block, 8 waves split N; ping-pong LDS A/B.
__global__ __launch_bounds__(512) void ActionVQVAE_49452253446164_kernel(
    const float* __restrict__ action,
    const u16* __restrict__ We1, const float* __restrict__ be1,
    const u16* __restrict__ We2, const float* __restrict__ be2,
    const u16* __restrict__ We3, const float* __restrict__ be3,
    const u16* __restrict__ E,
    const u16* __restrict__ Wd1, const float* __restrict__ bd1,
    const u16* __restrict__ Wd2, const float* __restrict__ bd2,
    const u16* __restrict__ Wh,  const float* __restrict__ bh,
    const float* __restrict__ enorms, float* __restrict__ sums,
    unsigned* __restrict__ counter, float* __restrict__ out)
{
    __shared__ u16   bufA[MROWS * SA];   // h1 -> enc(cols 0..127) -> d1
    __shared__ u16   bufB[MROWS * SA];   // h2 -> q(cols 0..127) -> d2
    __shared__ float red_val[NWAVE][MROWS];
    __shared__ int   red_idx[NWAVE][MROWS];
    __shared__ int   qidx[MROWS];
    __shared__ float wsum[2 * NWAVE];

    const int tid  = threadIdx.x;
    const int wave = tid >> 6;
    const int lane = tid & 63;
    const int lrow = lane & 15;
    const int quad = lane >> 4;
    const int kq   = quad * 8;
    const int base = blockIdx.x * MROWS;

    float vq_acc = 0.f, rec_acc = 0.f;

    // ---------- S1: h1 = relu(action @ We1^T + be1) -> A  (K=16 zero-padded to 32)
    {
        const int n0 = wave * 32;
        f32x4 acc[4][2];
        #pragma unroll
        for (int i = 0; i < 4; ++i)
            #pragma unroll
            for (int j = 0; j < 2; ++j) { f32x4 z = {0.f, 0.f, 0.f, 0.f}; acc[i][j] = z; }
        s16x8 a[4], b[2];
        s16x8 zf = {0, 0, 0, 0, 0, 0, 0, 0};
        #pragma unroll
        for (int i = 0; i < 4; ++i) a[i] = zf;
        #pragma unroll
        for (int j = 0; j < 2; ++j) b[j] = zf;
        if (quad < 2) {
            #pragma unroll
            for (int i = 0; i < 4; ++i) {
                const float* p = action + (base + i * 16 + lrow) * ADIM + kq;
                const float4 v0 = *reinterpret_cast<const float4*>(p);
                const float4 v1 = *reinterpret_cast<const float4*>(p + 4);
                s16x8 f;
                f[0] = (short)f2b(v0.x); f[1] = (short)f2b(v0.y);
                f[2] = (short)f2b(v0.z); f[3] = (short)f2b(v0.w);
                f[4] = (short)f2b(v1.x); f[5] = (short)f2b(v1.y);
                f[6] = (short)f2b(v1.z); f[7] = (short)f2b(v1.w);
                a[i] = f;
            }
            #pragma unroll
            for (int j = 0; j < 2; ++j) b[j] = ldb8(We1 + (n0 + j * 16 + lrow) * ADIM + kq);
        }
        #pragma unroll
        for (int i = 0; i < 4; ++i)
            #pragma unroll
            for (int j = 0; j < 2; ++j)
                acc[i][j] = __builtin_amdgcn_mfma_f32_16x16x32_bf16(a[i], b[j], acc[i][j], 0, 0, 0);
        epilogue_st<2>(bufA, be1, n0, lrow, quad, true, acc);
    }
    __syncthreads();

    // ---------- S2: h2 = relu(h1 @ We2^T + be2): A -> B
    {
        const int n0 = wave * 32;
        f32x4 acc[4][2];
        #pragma unroll
        for (int i = 0; i < 4; ++i)
            #pragma unroll
            for (int j = 0; j < 2; ++j) { f32x4 z = {0.f, 0.f, 0.f, 0.f}; acc[i][j] = z; }
        mm_tile<2, 8>(bufA, We2, HDIM, n0, lrow, kq, acc);
        epilogue_st<2>(bufB, be2, n0, lrow, quad, true, acc);
    }
    __syncthreads();

    // ---------- S3: enc = h2 @ We3^T + be3: B -> A cols 0..127
    {
        const int n0 = wave * 16;
        f32x4 acc[4][1];
        #pragma unroll
        for (int i = 0; i < 4; ++i) { f32x4 z = {0.f, 0.f, 0.f, 0.f}; acc[i][0] = z; }
        mm_tile<1, 8>(bufB, We3, HDIM, n0, lrow, kq, acc);
        epilogue_st<1>(bufA, be3, n0, lrow, quad, false, acc);
    }
    __syncthreads();

    // ---------- S4: argmin_k of d2 = |e_k|^2 - 2*enc.e_k  (|enc|^2 row-constant)
    {
        float minv[16]; int mini[16];
        #pragma unroll
        for (int s = 0; s < 16; ++s) { minv[s] = 3.4e38f; mini[s] = 0; }

        const int cb0 = wave * (KCODES / NWAVE);
        for (int cb = cb0; cb < cb0 + KCODES / NWAVE; cb += 32) {
            f32x4 acc[4][2];
            #pragma unroll
            for (int i = 0; i < 4; ++i)
                #pragma unroll
                for (int j = 0; j < 2; ++j) { f32x4 z = {0.f, 0.f, 0.f, 0.f}; acc[i][j] = z; }
            #pragma unroll
            for (int kc = 0; kc < 4; ++kc) {
                const int k = kc * 32 + kq;
                s16x8 a[4], b[2];
                #pragma unroll
                for (int i = 0; i < 4; ++i) a[i] = ldb8(bufA + (i * 16 + lrow) * SA + k);
                #pragma unroll
                for (int j = 0; j < 2; ++j) b[j] = ldb8(E + (cb + j * 16 + lrow) * DDIM + k);
                #pragma unroll
                for (int i = 0; i < 4; ++i)
                    #pragma unroll
                    for (int j = 0; j < 2; ++j)
                        acc[i][j] = __builtin_amdgcn_mfma_f32_16x16x32_bf16(a[i], b[j], acc[i][j], 0, 0, 0);
            }
            float en[2];
            #pragma unroll
            for (int j = 0; j < 2; ++j) en[j] = enorms[cb + j * 16 + lrow];
            #pragma unroll
            for (int i = 0; i < 4; ++i)
                #pragma unroll
                for (int j = 0; j < 2; ++j)
                    #pragma unroll
                    for (int r = 0; r < 4; ++r) {
                        const float d2 = en[j] - 2.f * acc[i][j][r];
                        const int s = i * 4 + r;
                        if (d2 < minv[s]) { minv[s] = d2; mini[s] = cb + j * 16 + lrow; }
                    }
        }
        // reduce across the 16 lanes of each quad-group (16 candidate cols per row-slot)
        #pragma unroll
        for (int off = 1; off < 16; off <<= 1) {
            #pragma unroll
            for (int s = 0; s < 16; ++s) {
                const float ov = __shfl_xor(minv[s], off, 64);
                const int   oi = __shfl_xor(mini[s], off, 64);
                if (ov < minv[s] || (ov == minv[s] && oi < mini[s])) { minv[s] = ov; mini[s] = oi; }
            }
        }
        if (lrow == 0) {
            #pragma unroll
            for (int i = 0; i < 4; ++i)
                #pragma unroll
                for (int r = 0; r < 4; ++r) {
                    red_val[wave][i * 16 + quad * 4 + r] = minv[i * 4 + r];
                    red_idx[wave][i * 16 + quad * 4 + r] = mini[i * 4 + r];
                }
        }
    }
    __syncthreads();
    if (tid < MROWS) {
        float bv = red_val[0][tid]; int bi = red_idx[0][tid];
        #pragma unroll
        for (int w = 1; w < NWAVE; ++w) {
            const float v = red_val[w][tid]; const int ii = red_idx[w][tid];
            if (v < bv || (v == bv && ii < bi)) { bv = v; bi = ii; }
        }
        qidx[tid] = bi;
    }
    __syncthreads();

    // ---------- S5: gather q -> B cols 0..127; vq += (enc - q)^2
    {
        const int row = tid >> 3;              // 64 rows, 8 threads/row
        const int c0  = (tid & 7) * 16;        // 16 cols/thread
        const int code = qidx[row];
        #pragma unroll
        for (int c = 0; c < 16; c += 8) {
            const u16x8 qv = *reinterpret_cast<const u16x8*>(E + code * DDIM + c0 + c);
            const u16x8 ev = *reinterpret_cast<const u16x8*>(bufA + row * SA + c0 + c);
            *reinterpret_cast<u16x8*>(bufB + row * SA + c0 + c) = qv;
            #pragma unroll
            for (int t = 0; t < 8; ++t) {
                const float d = b2f(ev[t]) - b2f(qv[t]);
                vq_acc += d * d;
            }
        }
    }
    __syncthreads();

    // ---------- S6: d1 = relu(q @ Wd1^T + bd1): B -> A
    {
        const int n0 = wave * 32;
        f32x4 acc[4][2];
        #pragma unroll
        for (int i = 0; i < 4; ++i)
            #pragma unroll
            for (int j = 0; j < 2; ++j) { f32x4 z = {0.f, 0.f, 0.f, 0.f}; acc[i][j] = z; }
        mm_tile<2, 4>(bufB, Wd1, DDIM, n0, lrow, kq, acc);
        epilogue_st<2>(bufA, bd1, n0, lrow, quad, true, acc);
    }
    __syncthreads();

    // ---------- S7: d2 = relu(d1 @ Wd2^T + bd2): A -> B
    {
        const int n0 = wave * 32;
        f32x4 acc[4][2];
        #pragma unroll
        for (int i = 0; i < 4; ++i)
            #pragma unroll
            for (int j = 0; j < 2; ++j) { f32x4 z = {0.f, 0.f, 0.f, 0.f}; acc[i][j] = z; }
        mm_tile<2, 8>(bufA, Wd2, HDIM, n0, lrow, kq, acc);
        epilogue_st<2>(bufB, bd2, n0, lrow, quad, true, acc);
    }
    __syncthreads();

    // ---------- S8: recons = tanh(d2 @ Wh^T + bh); rec += (recons - action)^2 (fp32)
    if (wave < 4) {
        const int m0 = wave * 16;
        f32x4 acc = {0.f, 0.f, 0.f, 0.f};
        #pragma unroll
        for (int kc = 0; kc < 8; ++kc) {
            const int k = kc * 32 + kq;
            s16x8 a = ldb8(bufB + (m0 + lrow) * SA + k);
            s16x8 b = ldb8(Wh + lrow * HDIM + k);
            acc = __builtin_amdgcn_mfma_f32_16x16x32_bf16(a, b, acc, 0, 0, 0);
        }
        const float bias = bh[lrow];
        #pragma unroll
        for (int r = 0; r < 4; ++r) {
            const int row = m0 + quad * 4 + r;
            const float v = tanhf(acc[r] + bias);
            const float av = action[(base + row) * ADIM + lrow];
            const float d = v - av;
            rec_acc += d * d;
        }
    }

    // ---------- block reduction + atomics + last-block finalize
    #pragma unroll
    for (int off = 1; off < 64; off <<= 1) {
        vq_acc  += __shfl_xor(vq_acc,  off, 64);
        rec_acc += __shfl_xor(rec_acc, off, 64);
    }
    if (lane == 0) { wsum[wave] = rec_acc; wsum[NWAVE + wave] = vq_acc; }
    __syncthreads();
    if (tid == 0) {
        float r = 0.f, v = 0.f;
        #pragma unroll
        for (int w = 0; w < NWAVE; ++w) { r += wsum[w]; v += wsum[NWAVE + w]; }
        atomicAdd(&sums[0], r);
        atomicAdd(&sums[1], v);
        __threadfence();
        const unsigned old = atomicAdd(counter, 1u);
        if (old == gridDim.x - 1) {
            const float s0 = atomicAdd(&sums[0], 0.f);   // coherent device-scope read
            const float s1 = atomicAdd(&sums[1], 0.f);
            const float recons_loss = s0 / (float)(BATCH * ADIM);
            const float vq_loss     = 1.25f * (s1 / (float)(BATCH * DDIM));
            out[0] = recons_loss + vq_loss;
        }
    }
}

extern "C" void kernel_launch(void* const* d_in, const int* in_sizes, int n_in,
                              void* d_out, int out_size, void* d_ws, size_t ws_size,
                              hipStream_t stream)
{
    const float* action = (const float*)d_in[0];
    const float* We1f = (const float*)d_in[1];
    const float* be1  = (const float*)d_in[2];
    const float* We2f = (const float*)d_in[3];
    const float* be2  = (const float*)d_in[4];
    const float* We3f = (const float*)d_in[5];
    const float* be3  = (const float*)d_in[6];
    const float* Ef   = (const float*)d_in[7];
    const float* Wd1f = (const float*)d_in[8];
    const float* bd1  = (const float*)d_in[9];
    const float* Wd2f = (const float*)d_in[10];
    const float* bd2  = (const float*)d_in[11];
    const float* Whf  = (const float*)d_in[12];
    const float* bh   = (const float*)d_in[13];

    float* ws = (float*)d_ws;          // [0..1] sums, [2..2049] enorms, [2050] counter
    u16* wb = (u16*)(ws + 2052);       // bf16 area, 16B-aligned
    u16* bE   = wb;                    // 262144
    u16* bWe1 = bE   + KCODES * DDIM;  // 4096
    u16* bWe2 = bWe1 + HDIM * ADIM;    // 65536
    u16* bWe3 = bWe2 + HDIM * HDIM;    // 32768
    u16* bWd1 = bWe3 + DDIM * HDIM;    // 32768
    u16* bWd2 = bWd1 + HDIM * DDIM;    // 65536
    u16* bWh  = bWd2 + HDIM * HDIM;    // 4096

    vqvae_prep<<<456, 256, 0, stream>>>(Ef, bE, We1f, bWe1, We2f, bWe2, We3f, bWe3,
                                        Wd1f, bWd1, Wd2f, bWd2, Whf, bWh, ws);
    ActionVQVAE_49452253446164_kernel<<<BATCH / MROWS, 512, 0, stream>>>(
        action, bWe1, be1, bWe2, be2, bWe3, be3,
        bE, bWd1, bd1, bWd2, bd2, bWh, bh,
        ws + 2, ws, (unsigned*)(ws + 2050), (float*)d_out);
}

// Round 6
// 166.363 us; speedup vs baseline: 1.1980x; 1.0170x over previous
//
#include <hip/hip_runtime.h>

#define BATCH  32768
#define ADIM   16
#define HDIM   256
#define DDIM   128
#define KCODES 2048
#define MROWS  64    // batch rows per block
#define SA     264   // LDS row stride in u16 (256 cols + 8 pad; 528 B, 16B-aligned)

typedef unsigned short u16;
typedef short s16x8 __attribute__((ext_vector_type(8)));   // 8 x bf16 bits (MFMA frag)
typedef u16   u16x8 __attribute__((ext_vector_type(8)));
typedef float f32x4 __attribute__((ext_vector_type(4)));

__device__ __forceinline__ float b2f(u16 u) {
    return __uint_as_float(((unsigned)u) << 16);
}
__device__ __forceinline__ u16 f2b(float f) {
    unsigned u = __float_as_uint(f);
    u += 0x7fffu + ((u >> 16) & 1u);   // RNE
    return (u16)(u >> 16);
}
__device__ __forceinline__ s16x8 ldb8(const u16* p) {
    return *reinterpret_cast<const s16x8*>(p);
}

// Packed-W GEMM: C(64 x NT*16) += A(64 x KC*32, LDS) * W^T.
// Wp is fragment-major: tile T=(jn*KT+kc) holds 64 lanes x 8 u16 (coalesced 16B/lane).
template<int NT, int KC>
__device__ __forceinline__ void mm_tp(const u16* __restrict__ A, const u16* __restrict__ Wp,
                                      const int KT, const int jn0,
                                      const int lane, const int lrow, const int kq,
                                      f32x4 (&acc)[4][NT])
{
    #pragma unroll
    for (int kc = 0; kc < KC; ++kc) {
        s16x8 a[4], b[NT];
        #pragma unroll
        for (int i = 0; i < 4; ++i) a[i] = ldb8(A + (i * 16 + lrow) * SA + kc * 32 + kq);
        #pragma unroll
        for (int j = 0; j < NT; ++j) b[j] = ldb8(Wp + (((jn0 + j) * KT + kc) << 9) + lane * 8);
        #pragma unroll
        for (int i = 0; i < 4; ++i)
            #pragma unroll
            for (int j = 0; j < NT; ++j)
                acc[i][j] = __builtin_amdgcn_mfma_f32_16x16x32_bf16(a[i], b[j], acc[i][j], 0, 0, 0);
    }
}

// Epilogue: bias (fp32) + optional relu, store bf16 to LDS. C/D: row=quad*4+r, col=lane&15.
template<int NT>
__device__ __forceinline__ void epilogue_st(u16* __restrict__ out,
                                            const float* __restrict__ bias, int n0,
                                            int lrow, int quad, bool relu, f32x4 (&acc)[4][NT])
{
    #pragma unroll
    for (int j = 0; j < NT; ++j) {
        const float bv = bias[n0 + j * 16 + lrow];
        #pragma unroll
        for (int i = 0; i < 4; ++i)
            #pragma unroll
            for (int r = 0; r < 4; ++r) {
                float v = acc[i][j][r] + bv;
                if (relu) v = fmaxf(v, 0.f);
                out[(i * 16 + quad * 4 + r) * SA + n0 + j * 16 + lrow] = f2b(v);
            }
    }
}

// ---------------- prep: fragment-pack all weights + E to bf16, E row norms, zero sums.
// packed[(T<<9) + lane*8 + t] = W[(j*16 + lane%16)*K + kc*32 + (lane/16)*8 + t], T=j*KT+kc.
// Blocks (4 tiles each): We2[0,32) We3[32,48) Wd1[48,64) Wd2[64,96) Wh[96,98) We1[98,102) E[102,230)
__global__ __launch_bounds__(256) void vqvae_prep(
    const float* __restrict__ Ef,   const float* __restrict__ We1f,
    const float* __restrict__ We2f, const float* __restrict__ We3f,
    const float* __restrict__ Wd1f, const float* __restrict__ Wd2f,
    const float* __restrict__ Whf,
    u16* __restrict__ Ep,   u16* __restrict__ We1p,
    u16* __restrict__ We2p, u16* __restrict__ We3p,
    u16* __restrict__ Wd1p, u16* __restrict__ Wd2p,
    u16* __restrict__ Whp,  float* __restrict__ ws)
{
    __shared__ float ep[4][16];
    const int b = blockIdx.x, tid = threadIdx.x;
    const int lane = tid & 63, wv = tid >> 6;
    const int lrow = lane & 15, quad = lane >> 4;

    if (b == 0 && tid < 3) {
        if (tid == 2) reinterpret_cast<unsigned*>(ws)[2] = 0u;
        else ws[tid] = 0.f;
    }

    if (b < 98) {
        const float* src; u16* dst; int KT, Tb;
        if      (b < 32) { src = We2f; dst = We2p; KT = 8; Tb = b * 4; }
        else if (b < 48) { src = We3f; dst = We3p; KT = 8; Tb = (b - 32) * 4; }
        else if (b < 64) { src = Wd1f; dst = Wd1p; KT = 4; Tb = (b - 48) * 4; }
        else if (b < 96) { src = Wd2f; dst = Wd2p; KT = 8; Tb = (b - 64) * 4; }
        else             { src = Whf;  dst = Whp;  KT = 8; Tb = (b - 96) * 4; }
        const int T = Tb + wv;
        const int j = T / KT, kc = T % KT;
        const float* p = src + (j * 16 + lrow) * (KT * 32) + kc * 32 + quad * 8;
        const float4 v0 = *reinterpret_cast<const float4*>(p);
        const float4 v1 = *reinterpret_cast<const float4*>(p + 4);
        u16x8 o;
        o[0] = f2b(v0.x); o[1] = f2b(v0.y); o[2] = f2b(v0.z); o[3] = f2b(v0.w);
        o[4] = f2b(v1.x); o[5] = f2b(v1.y); o[6] = f2b(v1.z); o[7] = f2b(v1.w);
        *reinterpret_cast<u16x8*>(dst + (T << 9) + lane * 8) = o;
    } else if (b < 102) {
        // We1 (256x16), K zero-padded to 32: KT=1, tile=j.
        const int T = (b - 98) * 4 + wv;
        u16x8 o = {0, 0, 0, 0, 0, 0, 0, 0};
        if (quad < 2) {
            const float* p = We1f + (T * 16 + lrow) * ADIM + quad * 8;
            const float4 v0 = *reinterpret_cast<const float4*>(p);
            const float4 v1 = *reinterpret_cast<const float4*>(p + 4);
            o[0] = f2b(v0.x); o[1] = f2b(v0.y); o[2] = f2b(v0.z); o[3] = f2b(v0.w);
            o[4] = f2b(v1.x); o[5] = f2b(v1.y); o[6] = f2b(v1.z); o[7] = f2b(v1.w);
        }
        *reinterpret_cast<u16x8*>(We1p + (T << 9) + lane * 8) = o;
    } else {
        // E (2048x128): KT=4; block covers one 16-code group jb, kc = wv. Also |e|^2.
        const int jb = b - 102;
        const int T = jb * 4 + wv;
        const float* p = Ef + (jb * 16 + lrow) * DDIM + wv * 32 + quad * 8;
        const float4 v0 = *reinterpret_cast<const float4*>(p);
        const float4 v1 = *reinterpret_cast<const float4*>(p + 4);
        u16x8 o;
        o[0] = f2b(v0.x); o[1] = f2b(v0.y); o[2] = f2b(v0.z); o[3] = f2b(v0.w);
        o[4] = f2b(v1.x); o[5] = f2b(v1.y); o[6] = f2b(v1.z); o[7] = f2b(v1.w);
        *reinterpret_cast<u16x8*>(Ep + (T << 9) + lane * 8) = o;
        float s = 0.f;
        #pragma unroll
        for (int t = 0; t < 8; ++t) { const float f = b2f(o[t]); s += f * f; }
        s += __shfl_xor(s, 16, 64);
        s += __shfl_xor(s, 32, 64);          // all 4 quads of this row combined
        if (lane < 16) ep[wv][lane] = s;
        __syncthreads();
        if (tid < 16) ws[4 + jb * 16 + tid] = ep[0][tid] + ep[1][tid] + ep[2][tid] + ep[3][tid];
    }
}

// ---------------- main fused kernel: 64 rows/block, 4 waves, ping-pong LDS, packed W/E.
__global__ __launch_bounds__(256) void ActionVQVAE_49452253446164_kernel(
    const float* __restrict__ action,
    const u16* __restrict__ We1p, const float* __restrict__ be1,
    const u16* __restrict__ We2p, const float* __restrict__ be2,
    const u16* __restrict__ We3p, const float* __restrict__ be3,
    const u16* __restrict__ Ep,   const float* __restrict__ enorms,
    const u16* __restrict__ Wd1p, const float* __restrict__ bd1,
    const u16* __restrict__ Wd2p, const float* __restrict__ bd2,
    const u16* __restrict__ Whp,  const float* __restrict__ bh,
    float* __restrict__ sums, unsigned* __restrict__ counter, float* __restrict__ out)
{
    __shared__ u16   bufA[MROWS * SA];   // h1 -> enc(cols 0..127) -> d1
    __shared__ u16   bufB[MROWS * SA];   // h2 -> q(cols 0..127) -> d2
    __shared__ float red_val[4][MROWS];
    __shared__ int   red_idx[4][MROWS];
    __shared__ int   qidx[MROWS];
    __shared__ float wsum[8];

    const int tid  = threadIdx.x;
    const int wave = tid >> 6;
    const int lane = tid & 63;
    const int lrow = lane & 15;
    const int quad = lane >> 4;
    const int kq   = quad * 8;
    const int base = blockIdx.x * MROWS;

    float vq_acc = 0.f, rec_acc = 0.f;

    // ---------- S1: h1 = relu(action @ We1^T + be1) -> A  (K=16 zero-padded to 32)
    {
        f32x4 acc[4][4];
        #pragma unroll
        for (int i = 0; i < 4; ++i)
            #pragma unroll
            for (int j = 0; j < 4; ++j) { f32x4 z = {0.f, 0.f, 0.f, 0.f}; acc[i][j] = z; }
        s16x8 a[4], b[4];
        s16x8 zf = {0, 0, 0, 0, 0, 0, 0, 0};
        #pragma unroll
        for (int i = 0; i < 4; ++i) a[i] = zf;
        if (quad < 2) {
            #pragma unroll
            for (int i = 0; i < 4; ++i) {
                const float* p = action + (base + i * 16 + lrow) * ADIM + kq;
                const float4 v0 = *reinterpret_cast<const float4*>(p);
                const float4 v1 = *reinterpret_cast<const float4*>(p + 4);
                s16x8 f;
                f[0] = (short)f2b(v0.x); f[1] = (short)f2b(v0.y);
                f[2] = (short)f2b(v0.z); f[3] = (short)f2b(v0.w);
                f[4] = (short)f2b(v1.x); f[5] = (short)f2b(v1.y);
                f[6] = (short)f2b(v1.z); f[7] = (short)f2b(v1.w);
                a[i] = f;
            }
        }
        #pragma unroll
        for (int j = 0; j < 4; ++j) b[j] = ldb8(We1p + ((wave * 4 + j) << 9) + lane * 8);
        #pragma unroll
        for (int i = 0; i < 4; ++i)
            #pragma unroll
            for (int j = 0; j < 4; ++j)
                acc[i][j] = __builtin_amdgcn_mfma_f32_16x16x32_bf16(a[i], b[j], acc[i][j], 0, 0, 0);
        epilogue_st<4>(bufA, be1, wave * 64, lrow, quad, true, acc);
    }
    __syncthreads();

    // ---------- S2: h2 = relu(h1 @ We2^T + be2): A -> B
    {
        f32x4 acc[4][4];
        #pragma unroll
        for (int i = 0; i < 4; ++i)
            #pragma unroll
            for (int j = 0; j < 4; ++j) { f32x4 z = {0.f, 0.f, 0.f, 0.f}; acc[i][j] = z; }
        mm_tp<4, 8>(bufA, We2p, 8, wave * 4, lane, lrow, kq, acc);
        epilogue_st<4>(bufB, be2, wave * 64, lrow, quad, true, acc);
    }
    __syncthreads();

    // ---------- S3: enc = h2 @ We3^T + be3: B -> A cols 0..127
    {
        f32x4 acc[4][2];
        #pragma unroll
        for (int i = 0; i < 4; ++i)
            #pragma unroll
            for (int j = 0; j < 2; ++j) { f32x4 z = {0.f, 0.f, 0.f, 0.f}; acc[i][j] = z; }
        mm_tp<2, 8>(bufB, We3p, 8, wave * 2, lane, lrow, kq, acc);
        epilogue_st<2>(bufA, be3, wave * 32, lrow, quad, false, acc);
    }
    __syncthreads();

    // ---------- S4: argmin_k of |e_k|^2 - 2*enc.e_k; wave sweeps 512 codes x 64 rows
    {
        s16x8 afr[4][4];                       // hoisted enc fragments [kc][i]
        #pragma unroll
        for (int kc = 0; kc < 4; ++kc) {
            const int k = kc * 32 + kq;
            #pragma unroll
            for (int i = 0; i < 4; ++i) afr[kc][i] = ldb8(bufA + (i * 16 + lrow) * SA + k);
        }
        float minv[16]; int mini[16];
        #pragma unroll
        for (int s = 0; s < 16; ++s) { minv[s] = 3.4e38f; mini[s] = 0; }

        const int tb0 = wave * 32;             // 16-code tile base (512 codes per wave)
        #pragma unroll
        for (int c = 0; c < 8; ++c) {
            const int tb = tb0 + c * 4;
            f32x4 acc[4][4];
            #pragma unroll
            for (int i = 0; i < 4; ++i)
                #pragma unroll
                for (int j = 0; j < 4; ++j) { f32x4 z = {0.f, 0.f, 0.f, 0.f}; acc[i][j] = z; }
            #pragma unroll
            for (int kc = 0; kc < 4; ++kc) {
                s16x8 b[4];
                #pragma unroll
                for (int j = 0; j < 4; ++j)
                    b[j] = ldb8(Ep + (((tb + j) * 4 + kc) << 9) + lane * 8);
                #pragma unroll
                for (int i = 0; i < 4; ++i)
                    #pragma unroll
                    for (int j = 0; j < 4; ++j)
                        acc[i][j] = __builtin_amdgcn_mfma_f32_16x16x32_bf16(afr[kc][i], b[j], acc[i][j], 0, 0, 0);
            }
            float en[4];
            #pragma unroll
            for (int j = 0; j < 4; ++j) en[j] = enorms[(tb + j) * 16 + lrow];
            #pragma unroll
            for (int i = 0; i < 4; ++i)
                #pragma unroll
                for (int j = 0; j < 4; ++j)
                    #pragma unroll
                    for (int r = 0; r < 4; ++r) {
                        const float d2 = en[j] - 2.f * acc[i][j][r];
                        const int s = i * 4 + r;
                        if (d2 < minv[s]) { minv[s] = d2; mini[s] = (tb + j) * 16 + lrow; }
                    }
        }
        #pragma unroll
        for (int off = 1; off < 16; off <<= 1) {
            #pragma unroll
            for (int s = 0; s < 16; ++s) {
                const float ov = __shfl_xor(minv[s], off, 64);
                const int   oi = __shfl_xor(mini[s], off, 64);
                if (ov < minv[s] || (ov == minv[s] && oi < mini[s])) { minv[s] = ov; mini[s] = oi; }
            }
        }
        if (lrow == 0) {
            #pragma unroll
            for (int i = 0; i < 4; ++i)
                #pragma unroll
                for (int r = 0; r < 4; ++r) {
                    red_val[wave][i * 16 + quad * 4 + r] = minv[i * 4 + r];
                    red_idx[wave][i * 16 + quad * 4 + r] = mini[i * 4 + r];
                }
        }
    }
    __syncthreads();
    if (tid < MROWS) {
        float bv = red_val[0][tid]; int bi = red_idx[0][tid];
        #pragma unroll
        for (int w = 1; w < 4; ++w) {
            const float v = red_val[w][tid]; const int ii = red_idx[w][tid];
            if (v < bv || (v == bv && ii < bi)) { bv = v; bi = ii; }
        }
        qidx[tid] = bi;
    }
    __syncthreads();

    // ---------- S5: gather q from packed E -> B cols 0..127; vq += (enc - q)^2
    {
        const int row = tid >> 2;              // 64 rows, 4 threads/row
        const int kc  = tid & 3;               // 32 cols (one kc-tile) per thread
        const int code = qidx[row];
        const u16* ebase = Ep + ((((code >> 4) * 4 + kc) << 9)) + (code & 15) * 8;
        #pragma unroll
        for (int q = 0; q < 4; ++q) {
            const u16x8 qv = *reinterpret_cast<const u16x8*>(ebase + q * 128);
            const int col = kc * 32 + q * 8;
            const u16x8 ev = *reinterpret_cast<const u16x8*>(bufA + row * SA + col);
            *reinterpret_cast<u16x8*>(bufB + row * SA + col) = qv;
            #pragma unroll
            for (int t = 0; t < 8; ++t) {
                const float d = b2f(ev[t]) - b2f(qv[t]);
                vq_acc += d * d;
            }
        }
    }
    __syncthreads();

    // ---------- S6: d1 = relu(q @ Wd1^T + bd1): B -> A
    {
        f32x4 acc[4][4];
        #pragma unroll
        for (int i = 0; i < 4; ++i)
            #pragma unroll
            for (int j = 0; j < 4; ++j) { f32x4 z = {0.f, 0.f, 0.f, 0.f}; acc[i][j] = z; }
        mm_tp<4, 4>(bufB, Wd1p, 4, wave * 4, lane, lrow, kq, acc);
        epilogue_st<4>(bufA, bd1, wave * 64, lrow, quad, true, acc);
    }
    __syncthreads();

    // ---------- S7: d2 = relu(d1 @ Wd2^T + bd2): A -> B
    {
        f32x4 acc[4][4];
        #pragma unroll
        for (int i = 0; i < 4; ++i)
            #pragma unroll
            for (int j = 0; j < 4; ++j) { f32x4 z = {0.f, 0.f, 0.f, 0.f}; acc[i][j] = z; }
        mm_tp<4, 8>(bufA, Wd2p, 8, wave * 4, lane, lrow, kq, acc);
        epilogue_st<4>(bufB, bd2, wave * 64, lrow, quad, true, acc);
    }
    __syncthreads();

    // ---------- S8: recons = tanh(d2 @ Wh^T + bh); rec += (recons - action)^2 (fp32)
    {
        const int m0 = wave * 16;
        f32x4 acc = {0.f, 0.f, 0.f, 0.f};
        #pragma unroll
        for (int kc = 0; kc < 8; ++kc) {
            s16x8 a = ldb8(bufB + (m0 + lrow) * SA + kc * 32 + kq);
            s16x8 b = ldb8(Whp + (kc << 9) + lane * 8);
            acc = __builtin_amdgcn_mfma_f32_16x16x32_bf16(a, b, acc, 0, 0, 0);
        }
        const float bias = bh[lrow];
        #pragma unroll
        for (int r = 0; r < 4; ++r) {
            const int row = m0 + quad * 4 + r;
            const float v = tanhf(acc[r] + bias);
            const float av = action[(base + row) * ADIM + lrow];
            const float d = v - av;
            rec_acc += d * d;
        }
    }

    // ---------- block reduction + atomics + last-block finalize
    #pragma unroll
    for (int off = 1; off < 64; off <<= 1) {
        vq_acc  += __shfl_xor(vq_acc,  off, 64);
        rec_acc += __shfl_xor(rec_acc, off, 64);
    }
    if (lane == 0) { wsum[wave] = rec_acc; wsum[4 + wave] = vq_acc; }
    __syncthreads();
    if (tid == 0) {
        atomicAdd(&sums[0], wsum[0] + wsum[1] + wsum[2] + wsum[3]);
        atomicAdd(&sums[1], wsum[4] + wsum[5] + wsum[6] + wsum[7]);
        __threadfence();
        const unsigned old = atomicAdd(counter, 1u);
        if (old == gridDim.x - 1) {
            const float s0 = atomicAdd(&sums[0], 0.f);
            const float s1 = atomicAdd(&sums[1], 0.f);
            const float recons_loss = s0 / (float)(BATCH * ADIM);
            const float vq_loss     = 1.25f * (s1 / (float)(BATCH * DDIM));
            out[0] = recons_loss + vq_loss;
        }
    }
}

extern "C" void kernel_launch(void* const* d_in, const int* in_sizes, int n_in,
                              void* d_out, int out_size, void* d_ws, size_t ws_size,
                              hipStream_t stream)
{
    const float* action = (const float*)d_in[0];
    const float* We1f = (const float*)d_in[1];
    const float* be1  = (const float*)d_in[2];
    const float* We2f = (const float*)d_in[3];
    const float* be2  = (const float*)d_in[4];
    const float* We3f = (const float*)d_in[5];
    const float* be3  = (const float*)d_in[6];
    const float* Ef   = (const float*)d_in[7];
    const float* Wd1f = (const float*)d_in[8];
    const float* bd1  = (const float*)d_in[9];
    const float* Wd2f = (const float*)d_in[10];
    const float* bd2  = (const float*)d_in[11];
    const float* Whf  = (const float*)d_in[12];
    const float* bh   = (const float*)d_in[13];

    float* ws = (float*)d_ws;          // [0]rec [1]vq [2]counter [3]pad [4..2052)enorms
    u16* wb = (u16*)(ws + 2052);       // packed bf16 area, 16B-aligned
    u16* Ep   = wb;                    // 262144
    u16* We1p = Ep   + KCODES * DDIM;  // 8192 (K padded to 32)
    u16* We2p = We1p + HDIM * 32;      // 65536
    u16* We3p = We2p + HDIM * HDIM;    // 32768
    u16* Wd1p = We3p + DDIM * HDIM;    // 32768
    u16* Wd2p = Wd1p + HDIM * DDIM;    // 65536
    u16* Whp  = Wd2p + HDIM * HDIM;    // 4096

    vqvae_prep<<<230, 256, 0, stream>>>(Ef, We1f, We2f, We3f, Wd1f, Wd2f, Whf,
                                        Ep, We1p, We2p, We3p, Wd1p, Wd2p, Whp, ws);
    ActionVQVAE_49452253446164_kernel<<<BATCH / MROWS, 256, 0, stream>>>(
        action, We1p, be1, We2p, be2, We3p, be3,
        Ep, ws + 4, Wd1p, bd1, Wd2p, bd2, Whp, bh,
        ws, (unsigned*)(ws + 2), (float*)d_out);
}

// Round 7
// 157.303 us; speedup vs baseline: 1.2669x; 1.0576x over previous
//
#include <hip/hip_runtime.h>

#define BATCH  32768
#define ADIM   16
#define HDIM   256
#define DDIM   128
#define KCODES 2048
#define MROWS  64    // batch rows per block
#define SA     264   // LDS row stride in u16 (256 cols + 8 pad; 528 B, 16B-aligned)

typedef unsigned short u16;
typedef short s16x8 __attribute__((ext_vector_type(8)));   // 8 x bf16 bits (MFMA frag)
typedef u16   u16x8 __attribute__((ext_vector_type(8)));
typedef float f32x4 __attribute__((ext_vector_type(4)));

__device__ __forceinline__ float b2f(u16 u) {
    return __uint_as_float(((unsigned)u) << 16);
}
__device__ __forceinline__ u16 f2b(float f) {
    unsigned u = __float_as_uint(f);
    u += 0x7fffu + ((u >> 16) & 1u);   // RNE
    return (u16)(u >> 16);
}
__device__ __forceinline__ s16x8 ldb8(const u16* p) {
    return *reinterpret_cast<const s16x8*>(p);
}
__device__ __forceinline__ s16x8 ldT(const u16* __restrict__ Wp, int T, int lane) {
    return ldb8(Wp + (T << 9) + lane * 8);   // packed tile T, 16B/lane coalesced
}

// GEMM with PRE preloaded kc-slices: C(64 x NT*16) += A(64xKC*32, LDS) * W^T.
template<int NT, int KC, int PRE>
__device__ __forceinline__ void gemm_pre(const u16* __restrict__ A,
                                         const u16* __restrict__ Wp, int KT, int jn0,
                                         const s16x8* __restrict__ preB,
                                         int lane, int lrow, int kq, f32x4 (&acc)[4][NT])
{
    #pragma unroll
    for (int kc = 0; kc < KC; ++kc) {
        s16x8 a[4], b[NT];
        #pragma unroll
        for (int i = 0; i < 4; ++i) a[i] = ldb8(A + (i * 16 + lrow) * SA + kc * 32 + kq);
        #pragma unroll
        for (int j = 0; j < NT; ++j)
            b[j] = (kc < PRE) ? preB[j * PRE + kc] : ldT(Wp, (jn0 + j) * KT + kc, lane);
        #pragma unroll
        for (int i = 0; i < 4; ++i)
            #pragma unroll
            for (int j = 0; j < NT; ++j)
                acc[i][j] = __builtin_amdgcn_mfma_f32_16x16x32_bf16(a[i], b[j], acc[i][j], 0, 0, 0);
    }
}

// Epilogue: bias + optional relu, store bf16 to LDS. C/D: row=quad*4+r, col=lane&15.
template<int NT>
__device__ __forceinline__ void epilogue_st(u16* __restrict__ out,
                                            const float* __restrict__ bias, int n0,
                                            int lrow, int quad, bool relu, f32x4 (&acc)[4][NT])
{
    #pragma unroll
    for (int j = 0; j < NT; ++j) {
        const float bv = bias[n0 + j * 16 + lrow];
        #pragma unroll
        for (int i = 0; i < 4; ++i)
            #pragma unroll
            for (int r = 0; r < 4; ++r) {
                float v = acc[i][j][r] + bv;
                if (relu) v = fmaxf(v, 0.f);
                out[(i * 16 + quad * 4 + r) * SA + n0 + j * 16 + lrow] = f2b(v);
            }
    }
}

// ---------------- prep: fragment-pack all weights + E to bf16, E row norms, zero sums.
// packed[(T<<9)+lane*8+t] = W[(j*16+lane%16)*K + kc*32 + (lane/16)*8 + t], T=j*KT+kc.
// Blocks: We2[0,32) We3[32,48) Wd1[48,64) Wd2[64,96) Wh[96,98) We1[98,102) E[102,230)
__global__ __launch_bounds__(256) void vqvae_prep(
    const float* __restrict__ Ef,   const float* __restrict__ We1f,
    const float* __restrict__ We2f, const float* __restrict__ We3f,
    const float* __restrict__ Wd1f, const float* __restrict__ Wd2f,
    const float* __restrict__ Whf,
    u16* __restrict__ Ep,   u16* __restrict__ We1p,
    u16* __restrict__ We2p, u16* __restrict__ We3p,
    u16* __restrict__ Wd1p, u16* __restrict__ Wd2p,
    u16* __restrict__ Whp,  float* __restrict__ ws)
{
    __shared__ float ep[4][16];
    const int b = blockIdx.x, tid = threadIdx.x;
    const int lane = tid & 63, wv = tid >> 6;
    const int lrow = lane & 15, quad = lane >> 4;

    if (b == 0 && tid < 3) {
        if (tid == 2) reinterpret_cast<unsigned*>(ws)[2] = 0u;
        else ws[tid] = 0.f;
    }

    if (b < 98) {
        const float* src; u16* dst; int KT, Tb;
        if      (b < 32) { src = We2f; dst = We2p; KT = 8; Tb = b * 4; }
        else if (b < 48) { src = We3f; dst = We3p; KT = 8; Tb = (b - 32) * 4; }
        else if (b < 64) { src = Wd1f; dst = Wd1p; KT = 4; Tb = (b - 48) * 4; }
        else if (b < 96) { src = Wd2f; dst = Wd2p; KT = 8; Tb = (b - 64) * 4; }
        else             { src = Whf;  dst = Whp;  KT = 8; Tb = (b - 96) * 4; }
        const int T = Tb + wv;
        const int j = T / KT, kc = T % KT;
        const float* p = src + (j * 16 + lrow) * (KT * 32) + kc * 32 + quad * 8;
        const float4 v0 = *reinterpret_cast<const float4*>(p);
        const float4 v1 = *reinterpret_cast<const float4*>(p + 4);
        u16x8 o;
        o[0] = f2b(v0.x); o[1] = f2b(v0.y); o[2] = f2b(v0.z); o[3] = f2b(v0.w);
        o[4] = f2b(v1.x); o[5] = f2b(v1.y); o[6] = f2b(v1.z); o[7] = f2b(v1.w);
        *reinterpret_cast<u16x8*>(dst + (T << 9) + lane * 8) = o;
    } else if (b < 102) {
        // We1 (256x16), K zero-padded to 32: KT=1, tile=j.
        const int T = (b - 98) * 4 + wv;
        u16x8 o = {0, 0, 0, 0, 0, 0, 0, 0};
        if (quad < 2) {
            const float* p = We1f + (T * 16 + lrow) * ADIM + quad * 8;
            const float4 v0 = *reinterpret_cast<const float4*>(p);
            const float4 v1 = *reinterpret_cast<const float4*>(p + 4);
            o[0] = f2b(v0.x); o[1] = f2b(v0.y); o[2] = f2b(v0.z); o[3] = f2b(v0.w);
            o[4] = f2b(v1.x); o[5] = f2b(v1.y); o[6] = f2b(v1.z); o[7] = f2b(v1.w);
        }
        *reinterpret_cast<u16x8*>(We1p + (T << 9) + lane * 8) = o;
    } else {
        // E (2048x128): KT=4; block covers one 16-code group jb, kc = wv. Also |e|^2.
        const int jb = b - 102;
        const int T = jb * 4 + wv;
        const float* p = Ef + (jb * 16 + lrow) * DDIM + wv * 32 + quad * 8;
        const float4 v0 = *reinterpret_cast<const float4*>(p);
        const float4 v1 = *reinterpret_cast<const float4*>(p + 4);
        u16x8 o;
        o[0] = f2b(v0.x); o[1] = f2b(v0.y); o[2] = f2b(v0.z); o[3] = f2b(v0.w);
        o[4] = f2b(v1.x); o[5] = f2b(v1.y); o[6] = f2b(v1.z); o[7] = f2b(v1.w);
        *reinterpret_cast<u16x8*>(Ep + (T << 9) + lane * 8) = o;
        float s = 0.f;
        #pragma unroll
        for (int t = 0; t < 8; ++t) { const float f = b2f(o[t]); s += f * f; }
        s += __shfl_xor(s, 16, 64);
        s += __shfl_xor(s, 32, 64);
        if (lane < 16) ep[wv][lane] = s;
        __syncthreads();
        if (tid < 16) ws[4 + jb * 16 + tid] = ep[0][tid] + ep[1][tid] + ep[2][tid] + ep[3][tid];
    }
}

// ---------------- main fused kernel: 64 rows/block, 8 waves, ping-pong LDS, packed W/E,
// explicit cross-barrier B-fragment prefetch.
__global__ __launch_bounds__(512) void ActionVQVAE_49452253446164_kernel(
    const float* __restrict__ action,
    const u16* __restrict__ We1p, const float* __restrict__ be1,
    const u16* __restrict__ We2p, const float* __restrict__ be2,
    const u16* __restrict__ We3p, const float* __restrict__ be3,
    const u16* __restrict__ Ep,   const float* __restrict__ enorms,
    const u16* __restrict__ Wd1p, const float* __restrict__ bd1,
    const u16* __restrict__ Wd2p, const float* __restrict__ bd2,
    const u16* __restrict__ Whp,  const float* __restrict__ bh,
    float* __restrict__ sums, unsigned* __restrict__ counter, float* __restrict__ out)
{
    __shared__ u16   bufA[MROWS * SA];   // h1 -> enc(cols 0..127) -> d1
    __shared__ u16   bufB[MROWS * SA];   // h2 -> q(cols 0..127) -> d2
    __shared__ float red_val[8][MROWS];
    __shared__ int   red_idx[8][MROWS];
    __shared__ int   qidx[MROWS];
    __shared__ float wsum[16];

    const int tid  = threadIdx.x;
    const int wave = tid >> 6;
    const int lane = tid & 63;
    const int lrow = lane & 15;
    const int quad = lane >> 4;
    const int kq   = quad * 8;
    const int base = blockIdx.x * MROWS;

    float vq_acc = 0.f, rec_acc = 0.f;
    s16x8 preB[8];   // cross-barrier prefetch staging

    // ---------- S1: h1 = relu(action @ We1^T + be1) -> A   (K=16 zero-padded; NT=2)
    {
        s16x8 b1[2];
        #pragma unroll
        for (int j = 0; j < 2; ++j) b1[j] = ldT(We1p, wave * 2 + j, lane);
        f32x4 acc[4][2];
        #pragma unroll
        for (int i = 0; i < 4; ++i)
            #pragma unroll
            for (int j = 0; j < 2; ++j) { f32x4 z = {0.f, 0.f, 0.f, 0.f}; acc[i][j] = z; }
        s16x8 a[4];
        s16x8 zf = {0, 0, 0, 0, 0, 0, 0, 0};
        #pragma unroll
        for (int i = 0; i < 4; ++i) a[i] = zf;
        if (quad < 2) {
            #pragma unroll
            for (int i = 0; i < 4; ++i) {
                const float* p = action + (base + i * 16 + lrow) * ADIM + kq;
                const float4 v0 = *reinterpret_cast<const float4*>(p);
                const float4 v1 = *reinterpret_cast<const float4*>(p + 4);
                s16x8 f;
                f[0] = (short)f2b(v0.x); f[1] = (short)f2b(v0.y);
                f[2] = (short)f2b(v0.z); f[3] = (short)f2b(v0.w);
                f[4] = (short)f2b(v1.x); f[5] = (short)f2b(v1.y);
                f[6] = (short)f2b(v1.z); f[7] = (short)f2b(v1.w);
                a[i] = f;
            }
        }
        #pragma unroll
        for (int i = 0; i < 4; ++i)
            #pragma unroll
            for (int j = 0; j < 2; ++j)
                acc[i][j] = __builtin_amdgcn_mfma_f32_16x16x32_bf16(a[i], b1[j], acc[i][j], 0, 0, 0);
        // prefetch S2 first 4 kc-slices (j=2 x kc=4) before the barrier
        #pragma unroll
        for (int j = 0; j < 2; ++j)
            #pragma unroll
            for (int kc = 0; kc < 4; ++kc)
                preB[j * 4 + kc] = ldT(We2p, (wave * 2 + j) * 8 + kc, lane);
        epilogue_st<2>(bufA, be1, wave * 32, lrow, quad, true, acc);
    }
    __syncthreads();

    // ---------- S2: h2 = relu(h1 @ We2^T + be2): A -> B   (NT=2, KC=8, PRE=4)
    {
        f32x4 acc[4][2];
        #pragma unroll
        for (int i = 0; i < 4; ++i)
            #pragma unroll
            for (int j = 0; j < 2; ++j) { f32x4 z = {0.f, 0.f, 0.f, 0.f}; acc[i][j] = z; }
        gemm_pre<2, 8, 4>(bufA, We2p, 8, wave * 2, preB, lane, lrow, kq, acc);
        // prefetch S3 first 4 kc-slices (NT=1)
        #pragma unroll
        for (int kc = 0; kc < 4; ++kc) preB[kc] = ldT(We3p, wave * 8 + kc, lane);
        epilogue_st<2>(bufB, be2, wave * 32, lrow, quad, true, acc);
    }
    __syncthreads();

    // ---------- S3: enc = h2 @ We3^T + be3: B -> A cols 0..127   (NT=1, KC=8, PRE=4)
    {
        f32x4 acc[4][1];
        #pragma unroll
        for (int i = 0; i < 4; ++i) { f32x4 z = {0.f, 0.f, 0.f, 0.f}; acc[i][0] = z; }
        gemm_pre<1, 8, 4>(bufB, We3p, 8, wave, preB, lane, lrow, kq, acc);
        // prefetch S4 chunk0 kc0..1 (j=4 x kc=2)
        #pragma unroll
        for (int j = 0; j < 4; ++j)
            #pragma unroll
            for (int kc = 0; kc < 2; ++kc)
                preB[j * 2 + kc] = ldT(Ep, (wave * 16 + j) * 4 + kc, lane);
        epilogue_st<1>(bufA, be3, wave * 16, lrow, quad, false, acc);
    }
    __syncthreads();

    // ---------- S4: argmin_k |e_k|^2 - 2*enc.e_k; each wave sweeps 256 codes (16 tiles)
    {
        s16x8 afr[4][4];                       // enc fragments [kc][i], hoisted once
        #pragma unroll
        for (int kc = 0; kc < 4; ++kc) {
            #pragma unroll
            for (int i = 0; i < 4; ++i)
                afr[kc][i] = ldb8(bufA + (i * 16 + lrow) * SA + kc * 32 + kq);
        }
        float minv[16]; int mini[16];
        #pragma unroll
        for (int s = 0; s < 16; ++s) { minv[s] = 3.4e38f; mini[s] = 0; }

        #pragma unroll
        for (int c = 0; c < 4; ++c) {
            const int tb = wave * 16 + c * 4;
            f32x4 acc[4][4];
            #pragma unroll
            for (int i = 0; i < 4; ++i)
                #pragma unroll
                for (int j = 0; j < 4; ++j) { f32x4 z = {0.f, 0.f, 0.f, 0.f}; acc[i][j] = z; }
            #pragma unroll
            for (int kc = 0; kc < 4; ++kc) {
                s16x8 b[4];
                #pragma unroll
                for (int j = 0; j < 4; ++j)
                    b[j] = (c == 0 && kc < 2) ? preB[j * 2 + kc]
                                              : ldT(Ep, (tb + j) * 4 + kc, lane);
                #pragma unroll
                for (int i = 0; i < 4; ++i)
                    #pragma unroll
                    for (int j = 0; j < 4; ++j)
                        acc[i][j] = __builtin_amdgcn_mfma_f32_16x16x32_bf16(afr[kc][i], b[j], acc[i][j], 0, 0, 0);
            }
            float en[4];
            #pragma unroll
            for (int j = 0; j < 4; ++j) en[j] = enorms[(tb + j) * 16 + lrow];
            #pragma unroll
            for (int i = 0; i < 4; ++i)
                #pragma unroll
                for (int j = 0; j < 4; ++j)
                    #pragma unroll
                    for (int r = 0; r < 4; ++r) {
                        const float d2 = fmaf(-2.f, acc[i][j][r], en[j]);
                        const int s = i * 4 + r;
                        if (d2 < minv[s]) { minv[s] = d2; mini[s] = (tb + j) * 16 + lrow; }
                    }
        }
        #pragma unroll
        for (int off = 1; off < 16; off <<= 1) {
            #pragma unroll
            for (int s = 0; s < 16; ++s) {
                const float ov = __shfl_xor(minv[s], off, 64);
                const int   oi = __shfl_xor(mini[s], off, 64);
                if (ov < minv[s] || (ov == minv[s] && oi < mini[s])) { minv[s] = ov; mini[s] = oi; }
            }
        }
        if (lrow == 0) {
            #pragma unroll
            for (int i = 0; i < 4; ++i)
                #pragma unroll
                for (int r = 0; r < 4; ++r) {
                    red_val[wave][i * 16 + quad * 4 + r] = minv[i * 4 + r];
                    red_idx[wave][i * 16 + quad * 4 + r] = mini[i * 4 + r];
                }
        }
        // prefetch S6 first 2 kc-slices (j=2 x kc=2) — independent of the reductions
        #pragma unroll
        for (int j = 0; j < 2; ++j)
            #pragma unroll
            for (int kc = 0; kc < 2; ++kc)
                preB[j * 2 + kc] = ldT(Wd1p, (wave * 2 + j) * 4 + kc, lane);
    }
    __syncthreads();
    if (tid < MROWS) {
        float bv = red_val[0][tid]; int bi = red_idx[0][tid];
        #pragma unroll
        for (int w = 1; w < 8; ++w) {
            const float v = red_val[w][tid]; const int ii = red_idx[w][tid];
            if (v < bv || (v == bv && ii < bi)) { bv = v; bi = ii; }
        }
        qidx[tid] = bi;
    }
    __syncthreads();

    // ---------- S5: gather q from packed E -> B cols 0..127; vq += (enc - q)^2
    {
        const int row  = tid >> 3;             // 64 rows, 8 threads/row
        const int t    = tid & 7;
        const int kc   = t >> 1;
        const int half = t & 1;
        const int code = qidx[row];
        const int T    = (code >> 4) * 4 + kc;
        const u16* eb  = Ep + (T << 9) + (code & 15) * 8;
        #pragma unroll
        for (int h = 0; h < 2; ++h) {
            const int qd  = half * 2 + h;
            const u16x8 qv = *reinterpret_cast<const u16x8*>(eb + qd * 128);
            const int col = kc * 32 + qd * 8;
            const u16x8 ev = *reinterpret_cast<const u16x8*>(bufA + row * SA + col);
            *reinterpret_cast<u16x8*>(bufB + row * SA + col) = qv;
            #pragma unroll
            for (int e = 0; e < 8; ++e) {
                const float d = b2f(ev[e]) - b2f(qv[e]);
                vq_acc += d * d;
            }
        }
    }
    __syncthreads();

    // ---------- S6: d1 = relu(q @ Wd1^T + bd1): B -> A   (NT=2, KC=4, PRE=2)
    {
        f32x4 acc[4][2];
        #pragma unroll
        for (int i = 0; i < 4; ++i)
            #pragma unroll
            for (int j = 0; j < 2; ++j) { f32x4 z = {0.f, 0.f, 0.f, 0.f}; acc[i][j] = z; }
        gemm_pre<2, 4, 2>(bufB, Wd1p, 4, wave * 2, preB, lane, lrow, kq, acc);
        // prefetch S7 first 4 kc-slices (j=2 x kc=4)
        #pragma unroll
        for (int j = 0; j < 2; ++j)
            #pragma unroll
            for (int kc = 0; kc < 4; ++kc)
                preB[j * 4 + kc] = ldT(Wd2p, (wave * 2 + j) * 8 + kc, lane);
        epilogue_st<2>(bufA, bd1, wave * 32, lrow, quad, true, acc);
    }
    __syncthreads();

    // ---------- S7: d2 = relu(d1 @ Wd2^T + bd2): A -> B   (NT=2, KC=8, PRE=4)
    {
        f32x4 acc[4][2];
        #pragma unroll
        for (int i = 0; i < 4; ++i)
            #pragma unroll
            for (int j = 0; j < 2; ++j) { f32x4 z = {0.f, 0.f, 0.f, 0.f}; acc[i][j] = z; }
        gemm_pre<2, 8, 4>(bufA, Wd2p, 8, wave * 2, preB, lane, lrow, kq, acc);
        // prefetch S8 Wh fragments (waves 0..3 only)
        if (wave < 4) {
            #pragma unroll
            for (int kc = 0; kc < 8; ++kc) preB[kc] = ldT(Whp, kc, lane);
        }
        epilogue_st<2>(bufB, bd2, wave * 32, lrow, quad, true, acc);
    }
    __syncthreads();

    // ---------- S8: recons = tanh(d2 @ Wh^T + bh); rec += (recons - action)^2 (fp32)
    if (wave < 4) {
        const int m0 = wave * 16;
        f32x4 acc = {0.f, 0.f, 0.f, 0.f};
        #pragma unroll
        for (int kc = 0; kc < 8; ++kc) {
            s16x8 a = ldb8(bufB + (m0 + lrow) * SA + kc * 32 + kq);
            acc = __builtin_amdgcn_mfma_f32_16x16x32_bf16(a, preB[kc], acc, 0, 0, 0);
        }
        const float bias = bh[lrow];
        #pragma unroll
        for (int r = 0; r < 4; ++r) {
            const int row = m0 + quad * 4 + r;
            const float v = tanhf(acc[r] + bias);
            const float av = action[(base + row) * ADIM + lrow];
            const float d = v - av;
            rec_acc += d * d;
        }
    }

    // ---------- block reduction + atomics + last-block finalize
    #pragma unroll
    for (int off = 1; off < 64; off <<= 1) {
        vq_acc  += __shfl_xor(vq_acc,  off, 64);
        rec_acc += __shfl_xor(rec_acc, off, 64);
    }
    if (lane == 0) { wsum[wave] = rec_acc; wsum[8 + wave] = vq_acc; }
    __syncthreads();
    if (tid == 0) {
        float r = 0.f, v = 0.f;
        #pragma unroll
        for (int w = 0; w < 8; ++w) { r += wsum[w]; v += wsum[8 + w]; }
        atomicAdd(&sums[0], r);
        atomicAdd(&sums[1], v);
        __threadfence();
        const unsigned old = atomicAdd(counter, 1u);
        if (old == gridDim.x - 1) {
            const float s0 = atomicAdd(&sums[0], 0.f);
            const float s1 = atomicAdd(&sums[1], 0.f);
            const float recons_loss = s0 / (float)(BATCH * ADIM);
            const float vq_loss     = 1.25f * (s1 / (float)(BATCH * DDIM));
            out[0] = recons_loss + vq_loss;
        }
    }
}

extern "C" void kernel_launch(void* const* d_in, const int* in_sizes, int n_in,
                              void* d_out, int out_size, void* d_ws, size_t ws_size,
                              hipStream_t stream)
{
    const float* action = (const float*)d_in[0];
    const float* We1f = (const float*)d_in[1];
    const float* be1  = (const float*)d_in[2];
    const float* We2f = (const float*)d_in[3];
    const float* be2  = (const float*)d_in[4];
    const float* We3f = (const float*)d_in[5];
    const float* be3  = (const float*)d_in[6];
    const float* Ef   = (const float*)d_in[7];
    const float* Wd1f = (const float*)d_in[8];
    const float* bd1  = (const float*)d_in[9];
    const float* Wd2f = (const float*)d_in[10];
    const float* bd2  = (const float*)d_in[11];
    const float* Whf  = (const float*)d_in[12];
    const float* bh   = (const float*)d_in[13];

    float* ws = (float*)d_ws;          // [0]rec [1]vq [2]counter [3]pad [4..2052)enorms
    u16* wb = (u16*)(ws + 2052);       // packed bf16 area, 16B-aligned
    u16* Ep   = wb;                    // 262144
    u16* We1p = Ep   + KCODES * DDIM;  // 8192 (K padded to 32)
    u16* We2p = We1p + HDIM * 32;      // 65536
    u16* We3p = We2p + HDIM * HDIM;    // 32768
    u16* Wd1p = We3p + DDIM * HDIM;    // 32768
    u16* Wd2p = Wd1p + HDIM * DDIM;    // 65536
    u16* Whp  = Wd2p + HDIM * HDIM;    // 4096

    vqvae_prep<<<230, 256, 0, stream>>>(Ef, We1f, We2f, We3f, Wd1f, Wd2f, Whf,
                                        Ep, We1p, We2p, We3p, Wd1p, Wd2p, Whp, ws);
    ActionVQVAE_49452253446164_kernel<<<BATCH / MROWS, 512, 0, stream>>>(
        action, We1p, be1, We2p, be2, We3p, be3,
        Ep, ws + 4, Wd1p, bd1, Wd2p, bd2, Whp, bh,
        ws, (unsigned*)(ws + 2), (float*)d_out);
}